// Round 12
// baseline (92.721 us; speedup 1.0000x reference)
//
#include <hip/hip_runtime.h>
#include <math.h>
#include <stdint.h>

#define EMBED 512
#define HID 16
#define SEQ 1024

typedef unsigned short u16;
typedef __attribute__((ext_vector_type(8))) __bf16 bf16x8;
typedef __attribute__((ext_vector_type(4))) float f32x4;

__device__ __forceinline__ u16 f2bf(float f) {
    unsigned u = __float_as_uint(f);
    unsigned r = (u + 0x7FFFu + ((u >> 16) & 1u)) >> 16;   // RNE
    return (u16)r;
}
__device__ __forceinline__ float bf2f(u16 h) {
    return __uint_as_float(((unsigned)h) << 16);
}
__device__ __forceinline__ void gload16(const void* g, void* d) {
    __builtin_amdgcn_global_load_lds(
        reinterpret_cast<const __attribute__((address_space(1))) unsigned int*>(
            reinterpret_cast<uintptr_t>(g)),
        reinterpret_cast<__attribute__((address_space(3))) unsigned int*>(
            reinterpret_cast<uintptr_t>(d)),
        16, 0, 0);
}

// ---------------- Kernel 1: fold W1 into Wq/Wk (+fused Wv hi/lo split) ----------------
__global__ __launch_bounds__(256) void wc_kernel(
    const float* __restrict__ Wq, const float* __restrict__ Wk,
    const float* __restrict__ W1, const float* __restrict__ Wvm,
    float* __restrict__ WcT, u16* __restrict__ wv_hi, u16* __restrict__ wv_lo)
{
    __shared__ float w1s[EMBED];
    int t = threadIdx.x;
    if (blockIdx.x >= 64) {
        int i = (blockIdx.x - 64) * 256 + t;       // float4 idx < 65536
        float4 v = ((const float4*)Wvm)[i];
        u16 h0 = f2bf(v.x), h1 = f2bf(v.y), h2 = f2bf(v.z), h3 = f2bf(v.w);
        ((ushort4*)wv_hi)[i] = make_ushort4(h0, h1, h2, h3);
        ((ushort4*)wv_lo)[i] = make_ushort4(f2bf(v.x - bf2f(h0)), f2bf(v.y - bf2f(h1)),
                                            f2bf(v.z - bf2f(h2)), f2bf(v.w - bf2f(h3)));
        return;
    }
    int h2 = blockIdx.x >> 1;         // 0..31
    int ab = h2 >> 4, h = h2 & 15;
    const float* Wmat = ab ? Wk : Wq;
    const float* w1row = W1 + (size_t)h * (2 * EMBED) + ab * EMBED;
    for (int f = t; f < EMBED; f += 256) w1s[f] = w1row[f];
    __syncthreads();
    int e0 = ((blockIdx.x & 1) << 8) + t;
    float acc = 0.f;
    #pragma unroll 16
    for (int f = 0; f < EMBED; ++f)
        acc += w1s[f] * Wmat[(size_t)f * EMBED + e0];
    WcT[(size_t)e0 * 32 + h2] = acc;
}

// ---------------- Kernel 2: EA/EB projections (+fused x_hi split) ----------------
__global__ __launch_bounds__(256) void ab_kernel(
    const float* __restrict__ x, const float* __restrict__ WcT,
    const float* __restrict__ b1,
    float* __restrict__ EA, float* __restrict__ EB, u16* __restrict__ x_hi)
{
    const float K2 = 2.8853900817779268f;   // 2*log2(e)
    __shared__ float xs[8][EMBED];
    __shared__ float wcs[EMBED * 32];
    int t = threadIdx.x;
    int s0 = blockIdx.x * 8;
    #pragma unroll
    for (int i = 0; i < 4; ++i) {
        int idx = t + i * 256;
        int row = idx >> 7, c4 = idx & 127;
        float4 vv = *(const float4*)(x + (size_t)(s0 + row) * EMBED + c4 * 4);
        *(float4*)&xs[row][c4 * 4] = vv;
        u16 h0 = f2bf(vv.x), h1 = f2bf(vv.y), h2 = f2bf(vv.z), h3 = f2bf(vv.w);
        ((ushort4*)x_hi)[(s0 + row) * 128 + c4] = make_ushort4(h0, h1, h2, h3);
    }
    #pragma unroll
    for (int i = 0; i < 16; ++i) {
        int idx = t + i * 256;
        ((float4*)wcs)[idx] = ((const float4*)WcT)[idx];
    }
    __syncthreads();
    int r = t >> 5, h2 = t & 31;
    const float* xr = xs[r];
    float acc = 0.f;
    #pragma unroll 8
    for (int k = 0; k < EMBED; ++k)
        acc += xr[k] * wcs[k * 32 + h2];
    int s = s0 + r;
    if (h2 < HID)
        EA[(size_t)s * HID + h2] = __builtin_amdgcn_exp2f(K2 * (acc + b1[h2]));
    else
        EB[(size_t)s * HID + (h2 - 16)] = __builtin_amdgcn_exp2f(K2 * acc);
}

// ---------------- staging helpers (128B-row tiles, XOR swizzle; proven) ----------------
template<int NR>
__device__ __forceinline__ void stageR(const u16* src, int ld, int kt,
                                       u16* ldsb, int t)
{
    int kb0 = kt << 7;
    #pragma unroll
    for (int i = 0; i < NR / 32; ++i) {
        int row  = i * 32 + (t >> 3);
        int colb = (((t & 7) ^ ((t >> 3) & 7)) << 4);
        const char* g = (const char*)src + (size_t)row * ((size_t)ld * 2) + kb0 + colb;
        gload16(g, (char*)ldsb + i * 4096 + ((t >> 6) << 10) + ((t & 63) << 4));
    }
}
__device__ __forceinline__ bf16x8 ldfrag(const u16* ldsb, int r, int s) {
    return *(const bf16x8*)((const char*)ldsb + r * 128 + (((s ^ (r & 7))) << 4));
}

// ---------------- Kernel 3: VT_hi[512][4096] = Wv(split) x X_hi^T ----------------
__global__ __launch_bounds__(256, 4) void vgemm_kernel(
    const u16* __restrict__ Ah, const u16* __restrict__ Al,
    const u16* __restrict__ Bh, u16* __restrict__ outH)
{
    constexpr int TOFF = 64 * 64;
    __shared__ __attribute__((aligned(16))) u16 lds[3 * TOFF];   // 24 KB
    int t = threadIdx.x;
    int l = t & 63, wid = t >> 6;
    int wm = (wid >> 1) * 32, wn = (wid & 1) * 32;
    int m0 = blockIdx.y * 64, n0 = blockIdx.x * 64;
    const u16* pAh = Ah + (size_t)m0 * EMBED;
    const u16* pAl = Al + (size_t)m0 * EMBED;
    const u16* pBh = Bh + (size_t)n0 * EMBED;
    f32x4 acc[2][2] = {};

    for (int kt = 0; kt < 8; ++kt) {
        stageR<64>(pAh, EMBED, kt, lds, t);
        stageR<64>(pAl, EMBED, kt, lds + TOFF, t);
        stageR<64>(pBh, EMBED, kt, lds + 2 * TOFF, t);
        __syncthreads();
        #pragma unroll
        for (int kk = 0; kk < 2; ++kk) {
            int sb = (kk << 2) + (l >> 4);
            bf16x8 ah[2], al2[2], bh[2];
            #pragma unroll
            for (int mf = 0; mf < 2; ++mf) {
                int r = wm + mf * 16 + (l & 15);
                ah[mf]  = ldfrag(lds, r, sb);
                al2[mf] = ldfrag(lds + TOFF, r, sb);
            }
            #pragma unroll
            for (int nf = 0; nf < 2; ++nf)
                bh[nf] = ldfrag(lds + 2 * TOFF, wn + nf * 16 + (l & 15), sb);
            #pragma unroll
            for (int mf = 0; mf < 2; ++mf)
                #pragma unroll
                for (int nf = 0; nf < 2; ++nf) {
                    acc[mf][nf] = __builtin_amdgcn_mfma_f32_16x16x32_bf16(ah[mf],  bh[nf], acc[mf][nf], 0, 0, 0);
                    acc[mf][nf] = __builtin_amdgcn_mfma_f32_16x16x32_bf16(al2[mf], bh[nf], acc[mf][nf], 0, 0, 0);
                }
        }
        __syncthreads();
    }

    int cr = (l >> 4) << 2, cc = l & 15;
    #pragma unroll
    for (int mf = 0; mf < 2; ++mf)
        #pragma unroll
        for (int nf = 0; nf < 2; ++nf)
            #pragma unroll
            for (int r = 0; r < 4; ++r)
                outH[(size_t)(m0 + wm + mf * 16 + cr + r) * 4096
                     + n0 + wn + nf * 16 + cc] = f2bf(acc[mf][nf][r]);
}

// ---------------- Kernel 4: fused — PRODUCER/CONSUMER wave specialization ----------
// 16 waves: waves 0-7 PRODUCE P (logits, pure VALU/trans), waves 8-15 CONSUME
// (stage V wave-locally + PV MFMA). Per chunk: producers build P(c+1) while
// consumers eat P(c) -> VALU and MFMA pipes run CONCURRENTLY per SIMD.
// One s_barrier per chunk; consumers use counted vmcnt(8) (their only vmem is V).
__global__ __launch_bounds__(1024) void fused_kernel(
    const float* __restrict__ EA, const float* __restrict__ EB,
    const float* __restrict__ w2, const u16* __restrict__ VT,
    float* __restrict__ out)
{
    __shared__ __attribute__((aligned(16))) u16 Vl[2][8][4096];    // buf x cons-wave x 8KB
    __shared__ __attribute__((aligned(16))) u16 Pl[2][2][1152];    // buf x hi/lo, 144B rows
    __shared__ float sred[8][16];
    __shared__ float srow[16];

    const float L2E = 1.4426950408889634f;
    int t = threadIdx.x;
    int l = t & 63, wid = t >> 6;
    int n = blockIdx.x;                      // 0..255
    int b = (n >> 1) & 3;                    // batch -> XCD pair (VT slice L2-resident)
    int m0 = ((((n & 1) << 5) | (n >> 3))) << 4;

    if (wid < 8) {
        // ================= PRODUCER =================
        int pw = wid;
        int prow = l & 15;
        int psl0 = (pw << 3) + ((l >> 4) << 1);      // kv slot base (2 per thread)

        const float4* Er = (const float4*)(EA + (size_t)(b * SEQ + m0 + prow) * HID);
        float4 A0 = Er[0], A1 = Er[1], A2 = Er[2], A3 = Er[3];
        const float4* Wq4 = (const float4*)w2;
        float4 u0 = Wq4[0], u1 = Wq4[1], u2 = Wq4[2], u3 = Wq4[3];
        float Pa1 = -2.f*u0.x, Pa2 = -2.f*u0.y, Pas = Pa1 + Pa2;
        float Pb1 = -2.f*u0.z, Pb2 = -2.f*u0.w, Pbs = Pb1 + Pb2;
        float Pc1 = -2.f*u1.x, Pc2 = -2.f*u1.y, Pcs = Pc1 + Pc2;
        float Pd1 = -2.f*u1.z, Pd2 = -2.f*u1.w, Pds = Pd1 + Pd2;
        float Pe1 = -2.f*u2.x, Pe2 = -2.f*u2.y, Pes = Pe1 + Pe2;
        float Pf1 = -2.f*u2.z, Pf2 = -2.f*u2.w, Pfs = Pf1 + Pf2;
        float Pg1 = -2.f*u3.x, Pg2 = -2.f*u3.y, Pgs = Pg1 + Pg2;
        float Ph1 = -2.f*u3.z, Ph2 = -2.f*u3.w, Phs = Ph1 + Ph2;
        float S0 = fmaxf(Pa1,0.f)+fmaxf(Pa2,0.f)+fmaxf(Pb1,0.f)+fmaxf(Pb2,0.f)
                 + fmaxf(Pc1,0.f)+fmaxf(Pc2,0.f)+fmaxf(Pd1,0.f)+fmaxf(Pd2,0.f)
                 + fmaxf(Pe1,0.f)+fmaxf(Pe2,0.f)+fmaxf(Pf1,0.f)+fmaxf(Pf2,0.f)
                 + fmaxf(Pg1,0.f)+fmaxf(Pg2,0.f)+fmaxf(Ph1,0.f)+fmaxf(Ph2,0.f);

#define QUAD(AV, BV, P1, P2, PS12, P3, P4, PS34) { \
    float e1 = AV.x * BV.x, e2 = AV.y * BV.y, e3 = AV.z * BV.z, e4 = AV.w * BV.w; \
    float D12 = fmaf(e1, e2, e1) + (e2 + 1.0f); \
    float N12 = fmaf((P2), e1, fmaf((P1), e2, (PS12))); \
    float D34 = fmaf(e3, e4, e3) + (e4 + 1.0f); \
    float N34 = fmaf((P4), e3, fmaf((P3), e4, (PS34))); \
    float Dq = D12 * D34; \
    float Nq = fmaf(N12, D34, N34 * D12); \
    s = fmaf(Nq, __builtin_amdgcn_rcpf(Dq), s); }

#define CALCLG(LG, v0, v1, v2, v3) { float s = 0.f; \
    QUAD(A0, v0, Pa1, Pa2, Pas, Pb1, Pb2, Pbs) \
    QUAD(A1, v1, Pc1, Pc2, Pcs, Pd1, Pd2, Pds) \
    QUAD(A2, v2, Pe1, Pe2, Pes, Pf1, Pf2, Pfs) \
    QUAD(A3, v3, Pg1, Pg2, Pgs, Ph1, Ph2, Phs) \
    LG = s; }

        const float* EBB = EB + ((size_t)(b << 10) + psl0) * HID;
#define LOADQ(d0,d1,d2,d3,d4,d5,d6,d7, c) { \
    const float4* _p = (const float4*)(EBB + (size_t)(c) * 1024); \
    d0=_p[0]; d1=_p[1]; d2=_p[2]; d3=_p[3]; d4=_p[4]; d5=_p[5]; d6=_p[6]; d7=_p[7]; }

#define PBODY(buf, R0,R1,R2,R3,R4,R5,R6,R7) { \
    float lgA, lgB; \
    CALCLG(lgA, R0, R1, R2, R3) \
    CALCLG(lgB, R4, R5, R6, R7) \
    float pA = __builtin_amdgcn_exp2f((lgA - S0) * L2E); \
    float pB = __builtin_amdgcn_exp2f((lgB - S0) * L2E); \
    s_part += pA + pB; \
    u16 hA = f2bf(pA), loA = f2bf(pA - bf2f(hA)); \
    u16 hB = f2bf(pB), loB = f2bf(pB - bf2f(hB)); \
    *(ushort2*)((char*)&Pl[buf][0][0] + prow * 144 + psl0 * 2) = make_ushort2(hA, hB); \
    *(ushort2*)((char*)&Pl[buf][1][0] + prow * 144 + psl0 * 2) = make_ushort2(loA, loB); }

        float s_part = 0.f;
        float4 qa0,qa1,qa2,qa3,qa4,qa5,qa6,qa7;
        float4 qb0,qb1,qb2,qb3,qb4,qb5,qb6,qb7;
        LOADQ(qa0,qa1,qa2,qa3,qa4,qa5,qa6,qa7, 0)
        LOADQ(qb0,qb1,qb2,qb3,qb4,qb5,qb6,qb7, 1)
        PBODY(0, qa0,qa1,qa2,qa3,qa4,qa5,qa6,qa7)
        LOADQ(qa0,qa1,qa2,qa3,qa4,qa5,qa6,qa7, 2)
        asm volatile("s_waitcnt lgkmcnt(0)" ::: "memory");
        __builtin_amdgcn_s_barrier();                    // barrier 1: P(0) ready

        #pragma unroll 1
        for (int cc = 0; cc < 8; ++cc) {
            int c = cc << 1;
            // between barrier(c) and barrier(c+1): build P(c+1) -> buf 1
            PBODY(1, qb0,qb1,qb2,qb3,qb4,qb5,qb6,qb7)
            if (c + 3 < 16) LOADQ(qb0,qb1,qb2,qb3,qb4,qb5,qb6,qb7, c + 3)
            asm volatile("s_waitcnt lgkmcnt(0)" ::: "memory");
            __builtin_amdgcn_s_barrier();
            // between barrier(c+1) and barrier(c+2): build P(c+2) -> buf 0
            if (cc < 7) {
                PBODY(0, qa0,qa1,qa2,qa3,qa4,qa5,qa6,qa7)
                if (c + 4 < 16) LOADQ(qa0,qa1,qa2,qa3,qa4,qa5,qa6,qa7, c + 4)
            }
            asm volatile("s_waitcnt lgkmcnt(0)" ::: "memory");
            __builtin_amdgcn_s_barrier();
        }
#undef PBODY
#undef LOADQ
#undef CALCLG
#undef QUAD
        // row-sum reduction (producers own all p values)
        float sv = s_part;
        sv += __shfl_xor(sv, 16);
        sv += __shfl_xor(sv, 32);
        if (l < 16) sred[pw][l] = sv;
        __syncthreads();
        if (t < 16) {
            float r0 = 0.f;
            #pragma unroll
            for (int ww = 0; ww < 8; ++ww) r0 += sred[ww][t];
            srow[t] = r0;
        }
        __syncthreads();
    } else {
        // ================= CONSUMER =================
        int cw = wid - 8;                            // owns d-rows [64cw, 64cw+64)
        f32x4 acc[4] = {};

        auto stageV = [&](int buf, int c) {
            size_t colbase = ((size_t)b << 10) + ((size_t)c << 6);   // u16 col in VT
            #pragma unroll
            for (int i = 0; i < 8; ++i) {
                int rl = (i << 3) + (l >> 3);                        // 0..63
                int s = (l & 7) ^ (rl & 7);
                const u16* g = VT + (size_t)((cw << 6) + rl) * 4096 + colbase + (s << 3);
                gload16(g, (char*)&Vl[buf][cw][0] + (i << 10) + (l << 4));
            }
        };
#define MFMA_BODY(pb) { \
    _Pragma("unroll") \
    for (int kh = 0; kh < 2; ++kh) { \
        bf16x8 pah = *(const bf16x8*)((const char*)&Pl[pb][0][0] + (l & 15) * 144 + kh * 64 + ((l >> 4) << 4)); \
        bf16x8 pal = *(const bf16x8*)((const char*)&Pl[pb][1][0] + (l & 15) * 144 + kh * 64 + ((l >> 4) << 4)); \
        _Pragma("unroll") \
        for (int nf = 0; nf < 4; ++nf) { \
            int rl = (nf << 4) + (l & 15); \
            int p_ = ((kh << 2) + (l >> 4)) ^ (rl & 7); \
            bf16x8 vb = *(const bf16x8*)((const char*)&Vl[pb][cw][0] + rl * 128 + (p_ << 4)); \
            acc[nf] = __builtin_amdgcn_mfma_f32_16x16x32_bf16(pah, vb, acc[nf], 0, 0, 0); \
            acc[nf] = __builtin_amdgcn_mfma_f32_16x16x32_bf16(pal, vb, acc[nf], 0, 0, 0); \
        } \
    } }

        stageV(0, 0);
        __builtin_amdgcn_s_barrier();                    // barrier 1: P(0) ready

        #pragma unroll 1
        for (int cc = 0; cc < 8; ++cc) {
            int c = cc << 1;
            stageV(1, c + 1);                            // prefetch V(c+1)
            asm volatile("s_waitcnt vmcnt(8)" ::: "memory");  // V(c) landed
            __builtin_amdgcn_sched_barrier(0);
            MFMA_BODY(0)                                 // consume P(c), V(c)
            __builtin_amdgcn_s_barrier();
            if (c + 2 < 16) {
                stageV(0, c + 2);
                asm volatile("s_waitcnt vmcnt(8)" ::: "memory");
            } else {
                asm volatile("s_waitcnt vmcnt(0)" ::: "memory");
            }
            __builtin_amdgcn_sched_barrier(0);
            MFMA_BODY(1)                                 // consume P(c+1), V(c+1)
            __builtin_amdgcn_s_barrier();
        }
#undef MFMA_BODY
        __syncthreads();                                 // matches producer's 2
        __syncthreads();
        int rr = (l >> 4) << 2;
        float i0 = __fdividef(1.f, srow[rr + 0]);
        float i1 = __fdividef(1.f, srow[rr + 1]);
        float i2 = __fdividef(1.f, srow[rr + 2]);
        float i3 = __fdividef(1.f, srow[rr + 3]);
        #pragma unroll
        for (int nf = 0; nf < 4; ++nf) {
            size_t base = (size_t)(b * SEQ + m0 + rr) * EMBED + (cw << 6) + (nf << 4) + (l & 15);
            out[base]             = acc[nf][0] * i0;
            out[base + EMBED]     = acc[nf][1] * i1;
            out[base + 2 * EMBED] = acc[nf][2] * i2;
            out[base + 3 * EMBED] = acc[nf][3] * i3;
        }
    }
}

extern "C" void kernel_launch(void* const* d_in, const int* in_sizes, int n_in,
                              void* d_out, int out_size, void* d_ws, size_t ws_size,
                              hipStream_t stream) {
    const float* x   = (const float*)d_in[0];
    const float* Wq  = (const float*)d_in[1];
    const float* Wk  = (const float*)d_in[2];
    const float* Wvm = (const float*)d_in[3];
    const float* W1  = (const float*)d_in[4];
    const float* b1  = (const float*)d_in[5];
    const float* w2  = (const float*)d_in[6];
    // d_in[7] = b2: softmax shift-invariant, unused.

    char* ws = (char*)d_ws;
    float* WcT   = (float*)(ws + 0);          //    65,536 B
    float* EA    = (float*)(ws + 65536);      //   262,144 B
    float* EB    = (float*)(ws + 327680);     //   262,144 B
    u16*   VT_hi = (u16*)(ws + 589824);       // 4,194,304 B  [512][4096]
    u16*   x_hi  = (u16*)(ws + 4784128);      // 4,194,304 B  [4096][512]
    u16*   wv_hi = (u16*)(ws + 8978432);      //   524,288 B
    u16*   wv_lo = (u16*)(ws + 9502720);      //   524,288 B
    float* out   = (float*)d_out;

    hipLaunchKernelGGL(wc_kernel, dim3(320), dim3(256), 0, stream,
                       Wq, Wk, W1, Wvm, WcT, wv_hi, wv_lo);
    hipLaunchKernelGGL(ab_kernel, dim3(512), dim3(256), 0, stream,
                       x, WcT, b1, EA, EB, x_hi);
    hipLaunchKernelGGL(vgemm_kernel, dim3(64, 8), dim3(256), 0, stream,
                       wv_hi, wv_lo, x_hi, VT_hi);
    hipLaunchKernelGGL(fused_kernel, dim3(256), dim3(1024), 0, stream,
                       EA, EB, w2, VT_hi, out);
}

// Round 13
// 65.228 us; speedup vs baseline: 1.4215x; 1.4215x over previous
//
#include <hip/hip_runtime.h>
#include <math.h>
#include <stdint.h>

#define EMBED 512
#define HID 16
#define SEQ 1024

typedef unsigned short u16;
typedef __attribute__((ext_vector_type(8))) __bf16 bf16x8;
typedef __attribute__((ext_vector_type(4))) float f32x4;

__device__ __forceinline__ u16 f2bf(float f) {
    unsigned u = __float_as_uint(f);
    unsigned r = (u + 0x7FFFu + ((u >> 16) & 1u)) >> 16;   // RNE
    return (u16)r;
}
__device__ __forceinline__ float bf2f(u16 h) {
    return __uint_as_float(((unsigned)h) << 16);
}
__device__ __forceinline__ void gload16(const void* g, void* d) {
    __builtin_amdgcn_global_load_lds(
        reinterpret_cast<const __attribute__((address_space(1))) unsigned int*>(
            reinterpret_cast<uintptr_t>(g)),
        reinterpret_cast<__attribute__((address_space(3))) unsigned int*>(
            reinterpret_cast<uintptr_t>(d)),
        16, 0, 0);
}

// ---------------- Kernel 1: fold W1 into Wq/Wk (+fused Wv hi/lo split) ----------------
__global__ __launch_bounds__(256) void wc_kernel(
    const float* __restrict__ Wq, const float* __restrict__ Wk,
    const float* __restrict__ W1, const float* __restrict__ Wvm,
    float* __restrict__ WcT, u16* __restrict__ wv_hi, u16* __restrict__ wv_lo)
{
    __shared__ float w1s[EMBED];
    int t = threadIdx.x;
    if (blockIdx.x >= 64) {
        int i = (blockIdx.x - 64) * 256 + t;       // float4 idx < 65536
        float4 v = ((const float4*)Wvm)[i];
        u16 h0 = f2bf(v.x), h1 = f2bf(v.y), h2 = f2bf(v.z), h3 = f2bf(v.w);
        ((ushort4*)wv_hi)[i] = make_ushort4(h0, h1, h2, h3);
        ((ushort4*)wv_lo)[i] = make_ushort4(f2bf(v.x - bf2f(h0)), f2bf(v.y - bf2f(h1)),
                                            f2bf(v.z - bf2f(h2)), f2bf(v.w - bf2f(h3)));
        return;
    }
    int h2 = blockIdx.x >> 1;         // 0..31
    int ab = h2 >> 4, h = h2 & 15;
    const float* Wmat = ab ? Wk : Wq;
    const float* w1row = W1 + (size_t)h * (2 * EMBED) + ab * EMBED;
    for (int f = t; f < EMBED; f += 256) w1s[f] = w1row[f];
    __syncthreads();
    int e0 = ((blockIdx.x & 1) << 8) + t;
    float acc = 0.f;
    #pragma unroll 16
    for (int f = 0; f < EMBED; ++f)
        acc += w1s[f] * Wmat[(size_t)f * EMBED + e0];
    WcT[(size_t)e0 * 32 + h2] = acc;
}

// ---------------- Kernel 2: EA/EB projections (+fused x_hi split) ----------------
__global__ __launch_bounds__(256) void ab_kernel(
    const float* __restrict__ x, const float* __restrict__ WcT,
    const float* __restrict__ b1,
    float* __restrict__ EA, float* __restrict__ EB, u16* __restrict__ x_hi)
{
    const float K2 = 2.8853900817779268f;   // 2*log2(e)
    __shared__ float xs[8][EMBED];
    __shared__ float wcs[EMBED * 32];
    int t = threadIdx.x;
    int s0 = blockIdx.x * 8;
    #pragma unroll
    for (int i = 0; i < 4; ++i) {
        int idx = t + i * 256;
        int row = idx >> 7, c4 = idx & 127;
        float4 vv = *(const float4*)(x + (size_t)(s0 + row) * EMBED + c4 * 4);
        *(float4*)&xs[row][c4 * 4] = vv;
        u16 h0 = f2bf(vv.x), h1 = f2bf(vv.y), h2 = f2bf(vv.z), h3 = f2bf(vv.w);
        ((ushort4*)x_hi)[(s0 + row) * 128 + c4] = make_ushort4(h0, h1, h2, h3);
    }
    #pragma unroll
    for (int i = 0; i < 16; ++i) {
        int idx = t + i * 256;
        ((float4*)wcs)[idx] = ((const float4*)WcT)[idx];
    }
    __syncthreads();
    int r = t >> 5, h2 = t & 31;
    const float* xr = xs[r];
    float acc = 0.f;
    #pragma unroll 8
    for (int k = 0; k < EMBED; ++k)
        acc += xr[k] * wcs[k * 32 + h2];
    int s = s0 + r;
    if (h2 < HID)
        EA[(size_t)s * HID + h2] = __builtin_amdgcn_exp2f(K2 * (acc + b1[h2]));
    else
        EB[(size_t)s * HID + (h2 - 16)] = __builtin_amdgcn_exp2f(K2 * acc);
}

// ---------------- staging helpers (128B-row tiles, XOR swizzle; proven) ----------------
template<int NR>
__device__ __forceinline__ void stageR(const u16* src, int ld, int kt,
                                       u16* ldsb, int t)
{
    int kb0 = kt << 7;
    #pragma unroll
    for (int i = 0; i < NR / 32; ++i) {
        int row  = i * 32 + (t >> 3);
        int colb = (((t & 7) ^ ((t >> 3) & 7)) << 4);
        const char* g = (const char*)src + (size_t)row * ((size_t)ld * 2) + kb0 + colb;
        gload16(g, (char*)ldsb + i * 4096 + ((t >> 6) << 10) + ((t & 63) << 4));
    }
}
__device__ __forceinline__ bf16x8 ldfrag(const u16* ldsb, int r, int s) {
    return *(const bf16x8*)((const char*)ldsb + r * 128 + (((s ^ (r & 7))) << 4));
}

// ---------------- Kernel 3: VT_hi[512][4096] = Wv(split) x X_hi^T ----------------
__global__ __launch_bounds__(256, 4) void vgemm_kernel(
    const u16* __restrict__ Ah, const u16* __restrict__ Al,
    const u16* __restrict__ Bh, u16* __restrict__ outH)
{
    constexpr int TOFF = 64 * 64;
    __shared__ __attribute__((aligned(16))) u16 lds[3 * TOFF];   // 24 KB
    int t = threadIdx.x;
    int l = t & 63, wid = t >> 6;
    int wm = (wid >> 1) * 32, wn = (wid & 1) * 32;
    int m0 = blockIdx.y * 64, n0 = blockIdx.x * 64;
    const u16* pAh = Ah + (size_t)m0 * EMBED;
    const u16* pAl = Al + (size_t)m0 * EMBED;
    const u16* pBh = Bh + (size_t)n0 * EMBED;
    f32x4 acc[2][2] = {};

    for (int kt = 0; kt < 8; ++kt) {
        stageR<64>(pAh, EMBED, kt, lds, t);
        stageR<64>(pAl, EMBED, kt, lds + TOFF, t);
        stageR<64>(pBh, EMBED, kt, lds + 2 * TOFF, t);
        __syncthreads();
        #pragma unroll
        for (int kk = 0; kk < 2; ++kk) {
            int sb = (kk << 2) + (l >> 4);
            bf16x8 ah[2], al2[2], bh[2];
            #pragma unroll
            for (int mf = 0; mf < 2; ++mf) {
                int r = wm + mf * 16 + (l & 15);
                ah[mf]  = ldfrag(lds, r, sb);
                al2[mf] = ldfrag(lds + TOFF, r, sb);
            }
            #pragma unroll
            for (int nf = 0; nf < 2; ++nf)
                bh[nf] = ldfrag(lds + 2 * TOFF, wn + nf * 16 + (l & 15), sb);
            #pragma unroll
            for (int mf = 0; mf < 2; ++mf)
                #pragma unroll
                for (int nf = 0; nf < 2; ++nf) {
                    acc[mf][nf] = __builtin_amdgcn_mfma_f32_16x16x32_bf16(ah[mf],  bh[nf], acc[mf][nf], 0, 0, 0);
                    acc[mf][nf] = __builtin_amdgcn_mfma_f32_16x16x32_bf16(al2[mf], bh[nf], acc[mf][nf], 0, 0, 0);
                }
        }
        __syncthreads();
    }

    int cr = (l >> 4) << 2, cc = l & 15;
    #pragma unroll
    for (int mf = 0; mf < 2; ++mf)
        #pragma unroll
        for (int nf = 0; nf < 2; ++nf)
            #pragma unroll
            for (int r = 0; r < 4; ++r)
                outH[(size_t)(m0 + wm + mf * 16 + cr + r) * 4096
                     + n0 + wn + nf * 16 + cc] = f2bf(acc[mf][nf][r]);
}

// ---------------- Kernel 4: logits + fixed-max softmax -> P (bf16, normalized) -------
// UNFUSED, barrier-free inner work: pure streaming VALU. 2 q-rows/block (EB reads
// amortized x2 -> 128 MB L2 total). tanh via e = EA*EB, 4-term QUAD fold,
// fixed-max bound S0 (no max pass). All state in NAMED registers (rule #20).
__global__ __launch_bounds__(256) void attn_kernel(
    const float* __restrict__ EA, const float* __restrict__ EB,
    const float* __restrict__ w2, u16* __restrict__ P)
{
    const float L2E = 1.4426950408889634f;
    __shared__ float redA[4], redB[4];
    int blk = blockIdx.x;             // 0..2047
    int b = blk >> 9;
    int i0 = (blk & 511) << 1;        // 2 rows per block
    int t = threadIdx.x;

    const float4* ArA = (const float4*)(EA + (size_t)(b * SEQ + i0) * HID);
    const float4* ArB = (const float4*)(EA + (size_t)(b * SEQ + i0 + 1) * HID);
    float4 X0 = ArA[0], X1 = ArA[1], X2 = ArA[2], X3 = ArA[3];
    float4 Y0 = ArB[0], Y1 = ArB[1], Y2 = ArB[2], Y3 = ArB[3];

    const float4* Wq4 = (const float4*)w2;
    float4 u0 = Wq4[0], u1 = Wq4[1], u2 = Wq4[2], u3 = Wq4[3];
    float Pa1 = -2.f*u0.x, Pa2 = -2.f*u0.y, Pas = Pa1 + Pa2;
    float Pb1 = -2.f*u0.z, Pb2 = -2.f*u0.w, Pbs = Pb1 + Pb2;
    float Pc1 = -2.f*u1.x, Pc2 = -2.f*u1.y, Pcs = Pc1 + Pc2;
    float Pd1 = -2.f*u1.z, Pd2 = -2.f*u1.w, Pds = Pd1 + Pd2;
    float Pe1 = -2.f*u2.x, Pe2 = -2.f*u2.y, Pes = Pe1 + Pe2;
    float Pf1 = -2.f*u2.z, Pf2 = -2.f*u2.w, Pfs = Pf1 + Pf2;
    float Pg1 = -2.f*u3.x, Pg2 = -2.f*u3.y, Pgs = Pg1 + Pg2;
    float Ph1 = -2.f*u3.z, Ph2 = -2.f*u3.w, Phs = Ph1 + Ph2;
    float S0 = fmaxf(Pa1,0.f)+fmaxf(Pa2,0.f)+fmaxf(Pb1,0.f)+fmaxf(Pb2,0.f)
             + fmaxf(Pc1,0.f)+fmaxf(Pc2,0.f)+fmaxf(Pd1,0.f)+fmaxf(Pd2,0.f)
             + fmaxf(Pe1,0.f)+fmaxf(Pe2,0.f)+fmaxf(Pf1,0.f)+fmaxf(Pf2,0.f)
             + fmaxf(Pg1,0.f)+fmaxf(Pg2,0.f)+fmaxf(Ph1,0.f)+fmaxf(Ph2,0.f);

#define QUAD(AV, BV, P1, P2, PS12, P3, P4, PS34) { \
    float e1 = AV.x * BV.x, e2 = AV.y * BV.y, e3 = AV.z * BV.z, e4 = AV.w * BV.w; \
    float D12 = fmaf(e1, e2, e1) + (e2 + 1.0f); \
    float N12 = fmaf((P2), e1, fmaf((P1), e2, (PS12))); \
    float D34 = fmaf(e3, e4, e3) + (e4 + 1.0f); \
    float N34 = fmaf((P4), e3, fmaf((P3), e4, (PS34))); \
    float Dq = D12 * D34; \
    float Nq = fmaf(N12, D34, N34 * D12); \
    s = fmaf(Nq, __builtin_amdgcn_rcpf(Dq), s); }

#define CALCLG(LG, W0, W1_, W2_, W3_, v0, v1, v2, v3) { float s = 0.f; \
    QUAD(W0,  v0, Pa1, Pa2, Pas, Pb1, Pb2, Pbs) \
    QUAD(W1_, v1, Pc1, Pc2, Pcs, Pd1, Pd2, Pds) \
    QUAD(W2_, v2, Pe1, Pe2, Pes, Pf1, Pf2, Pfs) \
    QUAD(W3_, v3, Pg1, Pg2, Pgs, Ph1, Ph2, Phs) \
    LG = s; }

    const float* EBB = EB + (size_t)(b << 10) * HID;
    float pa0, pa1, pa2, pa3, pb0, pb1, pb2, pb3;

#define DOC(c, PA, PB) { \
    const float4* q = (const float4*)(EBB + (size_t)(t + (c) * 256) * HID); \
    float4 v0 = q[0], v1 = q[1], v2 = q[2], v3 = q[3]; \
    float lgA, lgB; \
    CALCLG(lgA, X0, X1, X2, X3, v0, v1, v2, v3) \
    CALCLG(lgB, Y0, Y1, Y2, Y3, v0, v1, v2, v3) \
    PA = __builtin_amdgcn_exp2f((lgA - S0) * L2E); \
    PB = __builtin_amdgcn_exp2f((lgB - S0) * L2E); }

    DOC(0, pa0, pb0)
    DOC(1, pa1, pb1)
    DOC(2, pa2, pb2)
    DOC(3, pa3, pb3)
#undef DOC
#undef CALCLG
#undef QUAD

    float sA = (pa0 + pa1) + (pa2 + pa3);
    float sB = (pb0 + pb1) + (pb2 + pb3);
    #pragma unroll
    for (int o = 32; o > 0; o >>= 1) {
        sA += __shfl_xor(sA, o);
        sB += __shfl_xor(sB, o);
    }
    if ((t & 63) == 0) { redA[t >> 6] = sA; redB[t >> 6] = sB; }
    __syncthreads();
    float invA = __fdividef(1.f, (redA[0] + redA[1]) + (redA[2] + redA[3]));
    float invB = __fdividef(1.f, (redB[0] + redB[1]) + (redB[2] + redB[3]));

    size_t baseA = ((size_t)(b * SEQ) + i0) * SEQ;
    size_t baseB = baseA + SEQ;
    P[baseA + t      ] = f2bf(pa0 * invA);
    P[baseA + t + 256] = f2bf(pa1 * invA);
    P[baseA + t + 512] = f2bf(pa2 * invA);
    P[baseA + t + 768] = f2bf(pa3 * invA);
    P[baseB + t      ] = f2bf(pb0 * invB);
    P[baseB + t + 256] = f2bf(pb1 * invB);
    P[baseB + t + 512] = f2bf(pb2 * invB);
    P[baseB + t + 768] = f2bf(pb3 * invB);
}

// ---------------- Kernel 5: out = P @ V  (plain bf16 GEMM, per batch) ----------------
// M=1024/batch, N=512, K=1024. 128x64 tile, BK=64, double-buffered, 4 waves 2x2,
// wave-tile 64x32. A = P rows (ld=1024), B = VT rows (ld=4096, batch col-offset).
__global__ __launch_bounds__(256, 2) void pv_kernel(
    const u16* __restrict__ P, const u16* __restrict__ VT,
    float* __restrict__ out)
{
    constexpr int AOFF = 128 * 64;              // 8192 u16
    constexpr int BOFF = 64 * 64;               // 4096 u16
    constexpr int BUFW = AOFF + BOFF;           // 24 KB
    __shared__ __attribute__((aligned(16))) u16 lds[2 * BUFW];
    int t = threadIdx.x;
    int l = t & 63, wid = t >> 6;
    int wm = (wid >> 1) * 64, wn = (wid & 1) * 32;
    int m0 = blockIdx.y * 128, n0 = blockIdx.x * 64;
    int zb = blockIdx.z;
    const u16* pA = P + (size_t)zb * SEQ * SEQ + (size_t)m0 * SEQ;
    const u16* pB = VT + (size_t)n0 * 4096 + ((size_t)zb << 10);

    f32x4 acc[4][2] = {};

    auto STAGE = [&](int buf, int kt) {
        u16* base = lds + buf * BUFW;
        stageR<128>(pA, SEQ, kt, base, t);
        stageR<64>(pB, 4096, kt, base + AOFF, t);
    };
    auto COMPUTE = [&](int buf) {
        u16* lA = lds + buf * BUFW;
        u16* lB = lA + AOFF;
        #pragma unroll
        for (int kk = 0; kk < 2; ++kk) {
            int sb = (kk << 2) + (l >> 4);
            bf16x8 af[4], bf_[2];
            #pragma unroll
            for (int mf = 0; mf < 4; ++mf)
                af[mf] = ldfrag(lA, wm + mf * 16 + (l & 15), sb);
            #pragma unroll
            for (int nf = 0; nf < 2; ++nf)
                bf_[nf] = ldfrag(lB, wn + nf * 16 + (l & 15), sb);
            #pragma unroll
            for (int mf = 0; mf < 4; ++mf)
                #pragma unroll
                for (int nf = 0; nf < 2; ++nf)
                    acc[mf][nf] = __builtin_amdgcn_mfma_f32_16x16x32_bf16(af[mf], bf_[nf], acc[mf][nf], 0, 0, 0);
        }
    };

    STAGE(0, 0);
    __syncthreads();
    int cur = 0;
    for (int kt = 0; kt + 1 < 16; ++kt) {
        STAGE(cur ^ 1, kt + 1);
        COMPUTE(cur);
        __syncthreads();
        cur ^= 1;
    }
    COMPUTE(cur);

    int cr = (l >> 4) << 2, cc = l & 15;
    #pragma unroll
    for (int mf = 0; mf < 4; ++mf)
        #pragma unroll
        for (int nf = 0; nf < 2; ++nf)
            #pragma unroll
            for (int r = 0; r < 4; ++r)
                out[((size_t)(zb * SEQ) + m0 + wm + mf * 16 + cr + r) * EMBED
                    + n0 + wn + nf * 16 + cc] = acc[mf][nf][r];
}

extern "C" void kernel_launch(void* const* d_in, const int* in_sizes, int n_in,
                              void* d_out, int out_size, void* d_ws, size_t ws_size,
                              hipStream_t stream) {
    const float* x   = (const float*)d_in[0];
    const float* Wq  = (const float*)d_in[1];
    const float* Wk  = (const float*)d_in[2];
    const float* Wvm = (const float*)d_in[3];
    const float* W1  = (const float*)d_in[4];
    const float* b1  = (const float*)d_in[5];
    const float* w2  = (const float*)d_in[6];
    // d_in[7] = b2: softmax shift-invariant, unused.

    char* ws = (char*)d_ws;
    float* WcT   = (float*)(ws + 0);          //    65,536 B
    float* EA    = (float*)(ws + 65536);      //   262,144 B
    float* EB    = (float*)(ws + 327680);     //   262,144 B
    u16*   VT_hi = (u16*)(ws + 589824);       // 4,194,304 B  [512][4096]
    u16*   x_hi  = (u16*)(ws + 4784128);      // 4,194,304 B  [4096][512]
    u16*   wv_hi = (u16*)(ws + 8978432);      //   524,288 B
    u16*   wv_lo = (u16*)(ws + 9502720);      //   524,288 B
    u16*   P     = (u16*)(ws + 10027008);     // 8,388,608 B  [4096][1024]
    float* out   = (float*)d_out;

    hipLaunchKernelGGL(wc_kernel, dim3(320), dim3(256), 0, stream,
                       Wq, Wk, W1, Wvm, WcT, wv_hi, wv_lo);
    hipLaunchKernelGGL(ab_kernel, dim3(512), dim3(256), 0, stream,
                       x, WcT, b1, EA, EB, x_hi);
    hipLaunchKernelGGL(vgemm_kernel, dim3(64, 8), dim3(256), 0, stream,
                       wv_hi, wv_lo, x_hi, VT_hi);
    hipLaunchKernelGGL(attn_kernel, dim3(2048), dim3(256), 0, stream,
                       EA, EB, w2, P);
    hipLaunchKernelGGL(pv_kernel, dim3(8, 8, 4), dim3(256), 0, stream,
                       P, VT_hi, out);
}

// Round 14
// 60.656 us; speedup vs baseline: 1.5287x; 1.0754x over previous
//
#include <hip/hip_runtime.h>
#include <math.h>
#include <stdint.h>

#define EMBED 512
#define HID 16
#define SEQ 1024

typedef unsigned short u16;
typedef __attribute__((ext_vector_type(8))) __bf16 bf16x8;
typedef __attribute__((ext_vector_type(4))) float f32x4;

__device__ __forceinline__ u16 f2bf(float f) {
    unsigned u = __float_as_uint(f);
    unsigned r = (u + 0x7FFFu + ((u >> 16) & 1u)) >> 16;   // RNE
    return (u16)r;
}
__device__ __forceinline__ float bf2f(u16 h) {
    return __uint_as_float(((unsigned)h) << 16);
}
__device__ __forceinline__ void gload16(const void* g, void* d) {
    __builtin_amdgcn_global_load_lds(
        reinterpret_cast<const __attribute__((address_space(1))) unsigned int*>(
            reinterpret_cast<uintptr_t>(g)),
        reinterpret_cast<__attribute__((address_space(3))) unsigned int*>(
            reinterpret_cast<uintptr_t>(d)),
        16, 0, 0);
}

// ---------------- Kernel 1: prep — fold Wc rows + Wv split + x split ----------------
// A-matrix for the unified GEMM: rows 0..511 = Wv hi/lo, rows 512..543 = Wc hi/lo
// (Wc = [W1a@Wq ; W1b@Wk], 32x512), rows 544..575 = zero pad.
// blocks 0..63: fold (+pad-zero); 64..319: Wv split; 320..2367: x_hi split.
__global__ __launch_bounds__(256) void prep_kernel(
    const float* __restrict__ Wq, const float* __restrict__ Wk,
    const float* __restrict__ W1, const float* __restrict__ Wvm,
    const float* __restrict__ x,
    u16* __restrict__ AH, u16* __restrict__ AL, u16* __restrict__ x_hi)
{
    __shared__ float w1s[EMBED];
    int t = threadIdx.x;
    int blk = blockIdx.x;
    if (blk < 64) {
        int h2 = blk >> 1, half = blk & 1;
        int ab = h2 >> 4, h = h2 & 15;
        const float* Wmat = ab ? Wk : Wq;
        const float* w1row = W1 + (size_t)h * (2 * EMBED) + ab * EMBED;
        for (int f = t; f < EMBED; f += 256) w1s[f] = w1row[f];
        __syncthreads();
        int e0 = (half << 8) + t;
        float acc = 0.f;
        #pragma unroll 16
        for (int f = 0; f < EMBED; ++f)
            acc += w1s[f] * Wmat[(size_t)f * EMBED + e0];
        u16 hi = f2bf(acc);
        AH[(size_t)(512 + h2) * EMBED + e0] = hi;
        AL[(size_t)(512 + h2) * EMBED + e0] = f2bf(acc - bf2f(hi));
        AH[(size_t)(544 + h2) * EMBED + e0] = 0;        // pad rows
        AL[(size_t)(544 + h2) * EMBED + e0] = 0;
    } else if (blk < 320) {
        int i = (blk - 64) * 256 + t;                   // float4 idx < 65536
        float4 v = ((const float4*)Wvm)[i];
        u16 h0 = f2bf(v.x), h1 = f2bf(v.y), h2 = f2bf(v.z), h3 = f2bf(v.w);
        ((ushort4*)AH)[i] = make_ushort4(h0, h1, h2, h3);
        ((ushort4*)AL)[i] = make_ushort4(f2bf(v.x - bf2f(h0)), f2bf(v.y - bf2f(h1)),
                                         f2bf(v.z - bf2f(h2)), f2bf(v.w - bf2f(h3)));
    } else {
        int i = (blk - 320) * 256 + t;                  // float4 idx < 524288
        float4 v = ((const float4*)x)[i];
        ((ushort4*)x_hi)[i] = make_ushort4(f2bf(v.x), f2bf(v.y), f2bf(v.z), f2bf(v.w));
    }
}

// ---------------- staging helpers (128B-row tiles, XOR swizzle; proven) ----------------
template<int NR>
__device__ __forceinline__ void stageR(const u16* src, int ld, int kt,
                                       u16* ldsb, int t)
{
    int kb0 = kt << 7;
    #pragma unroll
    for (int i = 0; i < NR / 32; ++i) {
        int row  = i * 32 + (t >> 3);
        int colb = (((t & 7) ^ ((t >> 3) & 7)) << 4);
        const char* g = (const char*)src + (size_t)row * ((size_t)ld * 2) + kb0 + colb;
        gload16(g, (char*)ldsb + i * 4096 + ((t >> 6) << 10) + ((t & 63) << 4));
    }
}
__device__ __forceinline__ bf16x8 ldfrag(const u16* ldsb, int r, int s) {
    return *(const bf16x8*)((const char*)ldsb + r * 128 + (((s ^ (r & 7))) << 4));
}

// ---------------- Kernel 2: unified GEMM  [Wv;Wc;pad] x x_hi^T ----------------
// M=576 (9 m-tiles), N=4096, K=512. Rows <512 -> VT bf16; rows 512..527 -> EAt
// (exp2(K2*(v+b1))); rows 528..543 -> EBt (exp2(K2*v)); rows >=544 dropped.
__global__ __launch_bounds__(256, 4) void gemm_kernel(
    const u16* __restrict__ AH, const u16* __restrict__ AL,
    const u16* __restrict__ Bh, const float* __restrict__ b1,
    u16* __restrict__ VT, float* __restrict__ EAt, float* __restrict__ EBt)
{
    const float K2 = 2.8853900817779268f;   // 2*log2(e)
    constexpr int TOFF = 64 * 64;
    __shared__ __attribute__((aligned(16))) u16 lds[3 * TOFF];   // 24 KB
    int t = threadIdx.x;
    int l = t & 63, wid = t >> 6;
    int wm = (wid >> 1) * 32, wn = (wid & 1) * 32;
    int m0 = blockIdx.y * 64, n0 = blockIdx.x * 64;
    const u16* pAh = AH + (size_t)m0 * EMBED;
    const u16* pAl = AL + (size_t)m0 * EMBED;
    const u16* pBh = Bh + (size_t)n0 * EMBED;
    f32x4 acc[2][2] = {};

    for (int kt = 0; kt < 8; ++kt) {
        stageR<64>(pAh, EMBED, kt, lds, t);
        stageR<64>(pAl, EMBED, kt, lds + TOFF, t);
        stageR<64>(pBh, EMBED, kt, lds + 2 * TOFF, t);
        __syncthreads();
        #pragma unroll
        for (int kk = 0; kk < 2; ++kk) {
            int sb = (kk << 2) + (l >> 4);
            bf16x8 ah[2], al2[2], bh[2];
            #pragma unroll
            for (int mf = 0; mf < 2; ++mf) {
                int r = wm + mf * 16 + (l & 15);
                ah[mf]  = ldfrag(lds, r, sb);
                al2[mf] = ldfrag(lds + TOFF, r, sb);
            }
            #pragma unroll
            for (int nf = 0; nf < 2; ++nf)
                bh[nf] = ldfrag(lds + 2 * TOFF, wn + nf * 16 + (l & 15), sb);
            #pragma unroll
            for (int mf = 0; mf < 2; ++mf)
                #pragma unroll
                for (int nf = 0; nf < 2; ++nf) {
                    acc[mf][nf] = __builtin_amdgcn_mfma_f32_16x16x32_bf16(ah[mf],  bh[nf], acc[mf][nf], 0, 0, 0);
                    acc[mf][nf] = __builtin_amdgcn_mfma_f32_16x16x32_bf16(al2[mf], bh[nf], acc[mf][nf], 0, 0, 0);
                }
        }
        __syncthreads();
    }

    int cr = (l >> 4) << 2, cc = l & 15;
    #pragma unroll
    for (int mf = 0; mf < 2; ++mf)
        #pragma unroll
        for (int nf = 0; nf < 2; ++nf)
            #pragma unroll
            for (int r = 0; r < 4; ++r) {
                int gr = m0 + wm + mf * 16 + cr + r;
                int col = n0 + wn + nf * 16 + cc;
                float v = acc[mf][nf][r];
                if (gr < 512) {
                    VT[(size_t)gr * 4096 + col] = f2bf(v);
                } else if (gr < 528) {
                    EAt[(size_t)(gr - 512) * 4096 + col] =
                        __builtin_amdgcn_exp2f(K2 * (v + b1[gr - 512]));
                } else if (gr < 544) {
                    EBt[(size_t)(gr - 528) * 4096 + col] =
                        __builtin_amdgcn_exp2f(K2 * v);
                }
            }
}

// ---------------- Kernel 3: logits + fixed-max softmax -> P (bf16, normalized) -------
// Transposed EAt/EBt reads (coalesced across threads). tanh via e = EA*EB,
// 4-term QUAD fold, fixed-max bound S0. 2 q-rows/block.
__global__ __launch_bounds__(256) void attn_kernel(
    const float* __restrict__ EAt, const float* __restrict__ EBt,
    const float* __restrict__ w2, u16* __restrict__ P)
{
    const float L2E = 1.4426950408889634f;
    __shared__ float redA[4], redB[4];
    int blk = blockIdx.x;             // 0..2047
    int b = blk >> 9;
    int i0 = (blk & 511) << 1;        // 2 rows per block
    int t = threadIdx.x;
    int gA = (b << 10) + i0;

    float ax[HID], ay[HID];
    #pragma unroll
    for (int h = 0; h < HID; ++h) {
        ax[h] = EAt[(size_t)h * 4096 + gA];
        ay[h] = EAt[(size_t)h * 4096 + gA + 1];
    }

    float P1a[8], P2a[8], PSa[8];
    #pragma unroll
    for (int p = 0; p < 8; ++p) {
        float w1 = -2.f * w2[2 * p], w2_ = -2.f * w2[2 * p + 1];
        P1a[p] = w1; P2a[p] = w2_; PSa[p] = w1 + w2_;
    }
    float S0 = 0.f;
    #pragma unroll
    for (int p = 0; p < 8; ++p) S0 += fmaxf(P1a[p], 0.f) + fmaxf(P2a[p], 0.f);

    const float* EBb = EBt + (b << 10);
    float pa0, pa1, pa2, pa3, pb0, pb1, pb2, pb3;

#define DOC(c, PA, PB) { \
    int j = t + (c) * 256; \
    float bb[HID]; \
    _Pragma("unroll") \
    for (int h = 0; h < HID; ++h) bb[h] = EBb[(size_t)h * 4096 + j]; \
    float sA = 0.f, sB = 0.f; \
    _Pragma("unroll") \
    for (int q = 0; q < 4; ++q) { \
        int h0 = q << 2, p0 = q << 1, p1 = p0 + 1; \
        { float e1 = ax[h0]*bb[h0], e2 = ax[h0+1]*bb[h0+1]; \
          float e3 = ax[h0+2]*bb[h0+2], e4 = ax[h0+3]*bb[h0+3]; \
          float D12 = fmaf(e1, e2, e1) + (e2 + 1.0f); \
          float N12 = fmaf(P2a[p0], e1, fmaf(P1a[p0], e2, PSa[p0])); \
          float D34 = fmaf(e3, e4, e3) + (e4 + 1.0f); \
          float N34 = fmaf(P2a[p1], e3, fmaf(P1a[p1], e4, PSa[p1])); \
          sA = fmaf(fmaf(N12, D34, N34 * D12), __builtin_amdgcn_rcpf(D12 * D34), sA); } \
        { float e1 = ay[h0]*bb[h0], e2 = ay[h0+1]*bb[h0+1]; \
          float e3 = ay[h0+2]*bb[h0+2], e4 = ay[h0+3]*bb[h0+3]; \
          float D12 = fmaf(e1, e2, e1) + (e2 + 1.0f); \
          float N12 = fmaf(P2a[p0], e1, fmaf(P1a[p0], e2, PSa[p0])); \
          float D34 = fmaf(e3, e4, e3) + (e4 + 1.0f); \
          float N34 = fmaf(P2a[p1], e3, fmaf(P1a[p1], e4, PSa[p1])); \
          sB = fmaf(fmaf(N12, D34, N34 * D12), __builtin_amdgcn_rcpf(D12 * D34), sB); } \
    } \
    PA = __builtin_amdgcn_exp2f((sA - S0) * L2E); \
    PB = __builtin_amdgcn_exp2f((sB - S0) * L2E); }

    DOC(0, pa0, pb0)
    DOC(1, pa1, pb1)
    DOC(2, pa2, pb2)
    DOC(3, pa3, pb3)
#undef DOC

    float sA = (pa0 + pa1) + (pa2 + pa3);
    float sB = (pb0 + pb1) + (pb2 + pb3);
    #pragma unroll
    for (int o = 32; o > 0; o >>= 1) {
        sA += __shfl_xor(sA, o);
        sB += __shfl_xor(sB, o);
    }
    if ((t & 63) == 0) { redA[t >> 6] = sA; redB[t >> 6] = sB; }
    __syncthreads();
    float invA = __fdividef(1.f, (redA[0] + redA[1]) + (redA[2] + redA[3]));
    float invB = __fdividef(1.f, (redB[0] + redB[1]) + (redB[2] + redB[3]));

    size_t baseA = ((size_t)(b * SEQ) + i0) * SEQ;
    size_t baseB = baseA + SEQ;
    P[baseA + t      ] = f2bf(pa0 * invA);
    P[baseA + t + 256] = f2bf(pa1 * invA);
    P[baseA + t + 512] = f2bf(pa2 * invA);
    P[baseA + t + 768] = f2bf(pa3 * invA);
    P[baseB + t      ] = f2bf(pb0 * invB);
    P[baseB + t + 256] = f2bf(pb1 * invB);
    P[baseB + t + 512] = f2bf(pb2 * invB);
    P[baseB + t + 768] = f2bf(pb3 * invB);
}

// ---------------- Kernel 4: out = P @ V  (plain bf16 GEMM, per batch) ----------------
__global__ __launch_bounds__(256, 2) void pv_kernel(
    const u16* __restrict__ P, const u16* __restrict__ VT,
    float* __restrict__ out)
{
    constexpr int AOFF = 128 * 64;              // 8192 u16
    constexpr int BOFF = 64 * 64;               // 4096 u16
    constexpr int BUFW = AOFF + BOFF;           // 24 KB
    __shared__ __attribute__((aligned(16))) u16 lds[2 * BUFW];
    int t = threadIdx.x;
    int l = t & 63, wid = t >> 6;
    int wm = (wid >> 1) * 64, wn = (wid & 1) * 32;
    int m0 = blockIdx.y * 128, n0 = blockIdx.x * 64;
    int zb = blockIdx.z;
    const u16* pA = P + (size_t)zb * SEQ * SEQ + (size_t)m0 * SEQ;
    const u16* pB = VT + (size_t)n0 * 4096 + ((size_t)zb << 10);

    f32x4 acc[4][2] = {};

    auto STAGE = [&](int buf, int kt) {
        u16* base = lds + buf * BUFW;
        stageR<128>(pA, SEQ, kt, base, t);
        stageR<64>(pB, 4096, kt, base + AOFF, t);
    };
    auto COMPUTE = [&](int buf) {
        u16* lA = lds + buf * BUFW;
        u16* lB = lA + AOFF;
        #pragma unroll
        for (int kk = 0; kk < 2; ++kk) {
            int sb = (kk << 2) + (l >> 4);
            bf16x8 af[4], bf_[2];
            #pragma unroll
            for (int mf = 0; mf < 4; ++mf)
                af[mf] = ldfrag(lA, wm + mf * 16 + (l & 15), sb);
            #pragma unroll
            for (int nf = 0; nf < 2; ++nf)
                bf_[nf] = ldfrag(lB, wn + nf * 16 + (l & 15), sb);
            #pragma unroll
            for (int mf = 0; mf < 4; ++mf)
                #pragma unroll
                for (int nf = 0; nf < 2; ++nf)
                    acc[mf][nf] = __builtin_amdgcn_mfma_f32_16x16x32_bf16(af[mf], bf_[nf], acc[mf][nf], 0, 0, 0);
        }
    };

    STAGE(0, 0);
    __syncthreads();
    int cur = 0;
    for (int kt = 0; kt + 1 < 16; ++kt) {
        STAGE(cur ^ 1, kt + 1);
        COMPUTE(cur);
        __syncthreads();
        cur ^= 1;
    }
    COMPUTE(cur);

    int cr = (l >> 4) << 2, cc = l & 15;
    #pragma unroll
    for (int mf = 0; mf < 4; ++mf)
        #pragma unroll
        for (int nf = 0; nf < 2; ++nf)
            #pragma unroll
            for (int r = 0; r < 4; ++r)
                out[((size_t)(zb * SEQ) + m0 + wm + mf * 16 + cr + r) * EMBED
                    + n0 + wn + nf * 16 + cc] = acc[mf][nf][r];
}

extern "C" void kernel_launch(void* const* d_in, const int* in_sizes, int n_in,
                              void* d_out, int out_size, void* d_ws, size_t ws_size,
                              hipStream_t stream) {
    const float* x   = (const float*)d_in[0];
    const float* Wq  = (const float*)d_in[1];
    const float* Wk  = (const float*)d_in[2];
    const float* Wvm = (const float*)d_in[3];
    const float* W1  = (const float*)d_in[4];
    const float* b1  = (const float*)d_in[5];
    const float* w2  = (const float*)d_in[6];
    // d_in[7] = b2: softmax shift-invariant, unused.

    char* ws = (char*)d_ws;
    u16*   AH   = (u16*)(ws + 0);             //   589,824 B  [576][512]
    u16*   AL   = (u16*)(ws + 589824);        //   589,824 B
    u16*   x_hi = (u16*)(ws + 1179648);       // 4,194,304 B  [4096][512]
    u16*   VT   = (u16*)(ws + 5373952);       // 4,194,304 B  [512][4096]
    float* EAt  = (float*)(ws + 9568256);     //   262,144 B  [16][4096]
    float* EBt  = (float*)(ws + 9830400);     //   262,144 B  [16][4096]
    u16*   P    = (u16*)(ws + 10092544);      // 8,388,608 B  [4096][1024]
    float* out  = (float*)d_out;

    hipLaunchKernelGGL(prep_kernel, dim3(2368), dim3(256), 0, stream,
                       Wq, Wk, W1, Wvm, x, AH, AL, x_hi);
    hipLaunchKernelGGL(gemm_kernel, dim3(64, 9), dim3(256), 0, stream,
                       AH, AL, x_hi, b1, VT, EAt, EBt);
    hipLaunchKernelGGL(attn_kernel, dim3(2048), dim3(256), 0, stream,
                       EAt, EBt, w2, P);
    hipLaunchKernelGGL(pv_kernel, dim3(8, 8, 4), dim3(256), 0, stream,
                       P, VT, out);
}